// Round 1
// baseline (302.219 us; speedup 1.0000x reference)
//
#include <hip/hip_runtime.h>

#define SDIM 256
#define MDIM 16
#define CI 32
#define CO 32

constexpr float INV_S = 1.0f / 256.0f;
constexpr float TWO_PI_OVER_S = 6.28318530717958647692f / 256.0f;

__device__ __forceinline__ float4 f4zero() { return make_float4(0.f, 0.f, 0.f, 0.f); }

__device__ __forceinline__ void fma4(float4& a, float x, const float4 w) {
  a.x = fmaf(x, w.x, a.x);
  a.y = fmaf(x, w.y, a.y);
  a.z = fmaf(x, w.z, a.z);
  a.w = fmaf(x, w.w, a.w);
}

// -------------------------------------------------------------------------
// K1: truncated forward DHT. One block per (b, i) image.
//   Xh[k1,k2] = (1/256) * sum_{n1,n2} x[n1,n2] * cas(2*pi*(k1*n1 + k2*n2)/256)
// Stage 1 contracts n1 (per-column cos/sin sums, row-pair symmetry halves FMA),
// stage 2 contracts n2.
// -------------------------------------------------------------------------
__global__ __launch_bounds__(256, 2) void k_fwd(const float* __restrict__ x,
                                                float* __restrict__ xh) {
  __shared__ __align__(16) float cT[SDIM][MDIM];  // cos(2*pi*n*k/256), [n][k]
  __shared__ __align__(16) float sT[SDIM][MDIM];
  __shared__ float C1[MDIM][SDIM];                // [k1][n2]
  __shared__ float S1[MDIM][SDIM];

  const int t = threadIdx.x;  // 0..255 (= column n2 in stage 1)

  // build trig tables; (k*t)&255 keeps the argument exact and small
  #pragma unroll
  for (int k = 0; k < MDIM; ++k) {
    float sv, cv;
    sincosf(TWO_PI_OVER_S * (float)((k * t) & 255), &sv, &cv);
    cT[t][k] = cv;
    sT[t][k] = sv;
  }
  __syncthreads();

  const float* __restrict__ xp = x + (size_t)blockIdx.x * (SDIM * SDIM);

  float4 aC[4], aS[4];
  #pragma unroll
  for (int jj = 0; jj < 4; ++jj) { aC[jj] = f4zero(); aS[jj] = f4zero(); }

  // rows 0 and 128: sin terms vanish; cos row0 = 1, cos row128 = (-1)^k
  {
    float x0 = xp[t];
    float xm = xp[128 * SDIM + t];
    float e = x0 + xm;   // even k
    float od = x0 - xm;  // odd k
    #pragma unroll
    for (int jj = 0; jj < 4; ++jj) {
      aC[jj].x += e; aC[jj].y += od; aC[jj].z += e; aC[jj].w += od;
    }
  }

  // paired rows (n, 256-n), n = 1..127: cos equal, sin negated
  for (int base = 1; base + 8 <= 128; base += 8) {
    float xlo[8], xhi[8];
    #pragma unroll
    for (int j = 0; j < 8; ++j) {
      xlo[j] = xp[(base + j) * SDIM + t];
      xhi[j] = xp[(SDIM - base - j) * SDIM + t];
    }
    #pragma unroll
    for (int j = 0; j < 8; ++j) {
      const int n = base + j;
      float es = xlo[j] + xhi[j];
      float ds = xlo[j] - xhi[j];
      const float4* c4 = (const float4*)(&cT[n][0]);
      const float4* s4 = (const float4*)(&sT[n][0]);
      #pragma unroll
      for (int jj = 0; jj < 4; ++jj) {
        fma4(aC[jj], es, c4[jj]);
        fma4(aS[jj], ds, s4[jj]);
      }
    }
  }
  // tail rows 121..127
  #pragma unroll
  for (int n = 121; n < 128; ++n) {
    float lo = xp[n * SDIM + t];
    float hi = xp[(SDIM - n) * SDIM + t];
    float es = lo + hi, ds = lo - hi;
    const float4* c4 = (const float4*)(&cT[n][0]);
    const float4* s4 = (const float4*)(&sT[n][0]);
    #pragma unroll
    for (int jj = 0; jj < 4; ++jj) {
      fma4(aC[jj], es, c4[jj]);
      fma4(aS[jj], ds, s4[jj]);
    }
  }

  // scatter column sums to LDS: C1[k][n2=t]
  #pragma unroll
  for (int jj = 0; jj < 4; ++jj) {
    C1[4 * jj + 0][t] = aC[jj].x; C1[4 * jj + 1][t] = aC[jj].y;
    C1[4 * jj + 2][t] = aC[jj].z; C1[4 * jj + 3][t] = aC[jj].w;
    S1[4 * jj + 0][t] = aS[jj].x; S1[4 * jj + 1][t] = aS[jj].y;
    S1[4 * jj + 2][t] = aS[jj].z; S1[4 * jj + 3][t] = aS[jj].w;
  }
  __syncthreads();

  // stage 2: Xh[k1,k2] = (1/256) sum_n2 [ C1*(cos+sin) + S1*(cos-sin) ]
  const int k1 = t >> 4;
  const int k2 = t & 15;
  float acc = 0.f;
  #pragma unroll 8
  for (int n2 = 0; n2 < SDIM; ++n2) {
    float cv = cT[n2][k2];
    float sv = sT[n2][k2];
    acc = fmaf(C1[k1][n2], cv + sv, acc);
    acc = fmaf(S1[k1][n2], cv - sv, acc);
  }
  xh[(size_t)blockIdx.x * 256 + t] = acc * INV_S;
}

// -------------------------------------------------------------------------
// K2: mode mixing. One block per (b, o).
//   res = 0.5 * sum_i [ x1*(w + wn) + x1n*(w - wn) ],  n-index = (-k) mod 16
// -------------------------------------------------------------------------
__global__ __launch_bounds__(256, 2) void k_mix(const float* __restrict__ xh,
                                                const float* __restrict__ w,
                                                float* __restrict__ res) {
  __shared__ float xs[CI][256];
  __shared__ float wsm[CI][256];
  const int t = threadIdx.x;
  const int b = blockIdx.x >> 5;  // / CO
  const int o = blockIdx.x & 31;

  for (int i = 0; i < CI; ++i) {
    xs[i][t] = xh[((size_t)(b * CI + i)) * 256 + t];
    wsm[i][t] = w[((size_t)(i * CO + o)) * 256 + t];
  }
  __syncthreads();

  const int k1 = t >> 4, k2 = t & 15;
  const int tn = (((MDIM - k1) & 15) << 4) | ((MDIM - k2) & 15);
  float acc = 0.f;
  #pragma unroll 8
  for (int i = 0; i < CI; ++i) {
    float xp = xs[i][t], xn = xs[i][tn];
    float wp = wsm[i][t], wn = wsm[i][tn];
    acc = fmaf(xp, wp + wn, acc);
    acc = fmaf(xn, wp - wn, acc);
  }
  res[(size_t)blockIdx.x * 256 + t] = 0.5f * acc;
}

// -------------------------------------------------------------------------
// K3: truncated inverse DHT (same transform; ortho). One block per (b, o).
//   out[n1,n2] = (1/256) sum_{k1,k2<16} res * cas(2*pi*(k1*n1 + k2*n2)/256)
// Stage A contracts k1 -> U/V[n1][k2]; stage B contracts k2 per column.
// -------------------------------------------------------------------------
__global__ __launch_bounds__(256, 2) void k_inv(const float* __restrict__ res,
                                               float* __restrict__ out) {
  __shared__ __align__(16) float rs[256];
  __shared__ __align__(16) float U[SDIM][MDIM];
  __shared__ __align__(16) float V[SDIM][MDIM];
  const int t = threadIdx.x;

  rs[t] = res[(size_t)blockIdx.x * 256 + t];

  // per-thread twiddles at n = t
  float ct[16], st[16];
  #pragma unroll
  for (int k = 0; k < 16; ++k) {
    sincosf(TWO_PI_OVER_S * (float)((k * t) & 255), &st[k], &ct[k]);
  }
  __syncthreads();

  // stage A (thread t = n1): U[t][k2] = sum_k1 rs[k1,k2]*cos(2pi*k1*t/256); V: sin
  {
    float4 u[4], v[4];
    #pragma unroll
    for (int jj = 0; jj < 4; ++jj) { u[jj] = f4zero(); v[jj] = f4zero(); }
    #pragma unroll
    for (int kk1 = 0; kk1 < 16; ++kk1) {
      const float4* r4 = (const float4*)(&rs[kk1 * 16]);
      float c = ct[kk1], s = st[kk1];
      #pragma unroll
      for (int jj = 0; jj < 4; ++jj) {
        float4 r = r4[jj];
        fma4(u[jj], c, r);
        fma4(v[jj], s, r);
      }
    }
    float4* U4 = (float4*)(&U[t][0]);
    float4* V4 = (float4*)(&V[t][0]);
    #pragma unroll
    for (int jj = 0; jj < 4; ++jj) { U4[jj] = u[jj]; V4[jj] = v[jj]; }
  }
  __syncthreads();

  // stage B (thread t = n2): out[n1][t] = (1/256) sum_k2 [U*(c+s) + V*(c-s)]
  float cp[16], cm[16];
  #pragma unroll
  for (int k = 0; k < 16; ++k) { cp[k] = ct[k] + st[k]; cm[k] = ct[k] - st[k]; }

  float* __restrict__ op = out + (size_t)blockIdx.x * (SDIM * SDIM) + t;
  #pragma unroll 2
  for (int n1 = 0; n1 < SDIM; ++n1) {
    const float4* U4 = (const float4*)(&U[n1][0]);
    const float4* V4 = (const float4*)(&V[n1][0]);
    float acc = 0.f;
    #pragma unroll
    for (int jj = 0; jj < 4; ++jj) {
      float4 uu = U4[jj], vv = V4[jj];
      acc = fmaf(uu.x, cp[4 * jj + 0], acc); acc = fmaf(vv.x, cm[4 * jj + 0], acc);
      acc = fmaf(uu.y, cp[4 * jj + 1], acc); acc = fmaf(vv.y, cm[4 * jj + 1], acc);
      acc = fmaf(uu.z, cp[4 * jj + 2], acc); acc = fmaf(vv.z, cm[4 * jj + 2], acc);
      acc = fmaf(uu.w, cp[4 * jj + 3], acc); acc = fmaf(vv.w, cm[4 * jj + 3], acc);
    }
    op[n1 * SDIM] = acc * INV_S;
  }
}

extern "C" void kernel_launch(void* const* d_in, const int* in_sizes, int n_in,
                              void* d_out, int out_size, void* d_ws, size_t ws_size,
                              hipStream_t stream) {
  const float* x = (const float*)d_in[0];   // [16, 32, 256, 256] f32
  const float* w = (const float*)d_in[1];   // [32, 32, 16, 16]  f32
  float* out = (float*)d_out;               // [16, 32, 256, 256] f32

  float* xh  = (float*)d_ws;                // [16, 32, 16, 16]  (512 KB)
  float* res = (float*)d_ws + 512 * 256;    // [16, 32, 16, 16]  (512 KB)

  k_fwd<<<16 * CI, 256, 0, stream>>>(x, xh);        // 512 blocks
  k_mix<<<16 * CO, 256, 0, stream>>>(xh, w, res);   // 512 blocks
  k_inv<<<16 * CO, 256, 0, stream>>>(res, out);     // 512 blocks
}